// Round 24
// baseline (30.128 us; speedup 1.0000x reference)
//
#include <hip/hip_runtime.h>

// PSRoIPool (R-FCN), VERIFIED semantics (r23 pass, absmax 3.05e-5):
// features [4,490,38,38] f32, rois [256,5] f32, out [256,10,7,7] f32.
// CRITICAL numerics (do not touch):
//  - bin = roi * fl32(1/7)  (reciprocal multiply, NOT division) — matches the
//    reference's strength-reduced division; flips exact-integer end
//    boundaries (7|16*roi set) to N+eps -> ceil N+1. r1-r22 forensics.
//  - boundary = fl32(fl32(p*bin) + start): two roundings, fma blocked by an
//    asm opacity barrier; fp contract off.
// r24 optimization: window is provably <=7x7 (bin<=5.44 => ceil+1<=7), so
// fully unroll with predicated clamped loads: 49 independent loads, one
// vmcnt wait, no divergent variable-trip loops (we are latency-bound:
// ~1.9 waves/SIMD, L2-warm scattered reads). Masked +0.0f adds keep the
// accumulation bit-identical to the r23 pass.

#pragma clang fp contract(off)

#define PS 7
#define DD 10
#define CC 490
#define HH 38
#define WW 38

__device__ __forceinline__ float mul_add_strict_f32(float a, float b, float c) {
#pragma clang fp contract(off)
    float p = a * b;
    asm volatile("" : "+v"(p));   // block fma contraction
    return p + c;
}

__global__ __launch_bounds__(256) void psroi_pool_kernel(
    const float* __restrict__ feat,
    const float* __restrict__ rois,
    float* __restrict__ out,
    int total)
{
#pragma clang fp contract(off)
    int idx = blockIdx.x * blockDim.x + threadIdx.x;
    if (idx >= total) return;

    int pw = idx % PS;
    int ph = (idx / PS) % PS;
    int d  = (idx / (PS * PS)) % DD;
    int r  = idx / (PS * PS * DD);

    const float* roi = rois + (size_t)r * 5;
    int b = (int)roi[0];

    float xs = rintf(roi[1]) * 0.0625f;
    float ys = rintf(roi[2]) * 0.0625f;
    float xe = rintf(roi[3] + 1.0f) * 0.0625f;
    float ye = rintf(roi[4] + 1.0f) * 0.0625f;

    float roi_w = fmaxf(xe - xs, 0.1f);
    float roi_h = fmaxf(ye - ys, 0.1f);

    // RECIPROCAL MULTIPLY (verified): bin = roi * fl32(1/7)
    const float RECIP7 = 1.0f / 7.0f;
    float bin_w = roi_w * RECIP7;
    float bin_h = roi_h * RECIP7;

    float hs_f = floorf(mul_add_strict_f32((float)ph,       bin_h, ys));
    float he_f = ceilf (mul_add_strict_f32((float)(ph + 1), bin_h, ys));
    float ws_f = floorf(mul_add_strict_f32((float)pw,       bin_w, xs));
    float we_f = ceilf (mul_add_strict_f32((float)(pw + 1), bin_w, xs));

    int hstart = (int)fminf(fmaxf(hs_f, 0.0f), (float)HH);
    int hend   = (int)fminf(fmaxf(he_f, 0.0f), (float)HH);
    int wstart = (int)fminf(fmaxf(ws_f, 0.0f), (float)WW);
    int wend   = (int)fminf(fmaxf(we_f, 0.0f), (float)WW);

    int c = (d * PS + ph) * PS + pw;
    const float* fp = feat + ((size_t)b * CC + c) * (HH * WW);

    // Fully unrolled 7x7 predicated window sum: 49 independent loads
    // (addresses clamped in-plane), masked adds of +0.0f preserve the exact
    // ascending accumulation order of the verified kernel.
    float sum = 0.0f;
#pragma unroll
    for (int hh = 0; hh < 7; ++hh) {
        int h  = hstart + hh;
        bool vh = (h < hend);
        int hc = (h < HH - 1) ? h : (HH - 1);
        const float* row = fp + hc * WW;
#pragma unroll
        for (int ww = 0; ww < 7; ++ww) {
            int w  = wstart + ww;
            bool vw = (w < wend);
            int wc = (w < WW - 1) ? w : (WW - 1);
            float v = row[wc];
            sum += (vh && vw) ? v : 0.0f;
        }
    }

    int cnt = (hend - hstart) * (wend - wstart);
    out[idx] = (cnt > 0) ? (sum / (float)cnt) : 0.0f;
}

extern "C" void kernel_launch(void* const* d_in, const int* in_sizes, int n_in,
                              void* d_out, int out_size, void* d_ws, size_t ws_size,
                              hipStream_t stream) {
    const float* feat = (const float*)d_in[0];
    const float* rois = (const float*)d_in[1];
    float* out = (float*)d_out;

    int total = out_size;  // 125440
    int block = 256;
    int grid = (total + block - 1) / block;
    psroi_pool_kernel<<<grid, block, 0, stream>>>(feat, rois, out, total);
}

// Round 25
// 10.062 us; speedup vs baseline: 2.9943x; 2.9943x over previous
//
#include <hip/hip_runtime.h>

// PSRoIPool (R-FCN), VERIFIED semantics (r23 pass, absmax 3.05e-5, 11.0 µs):
// features [4,490,38,38] f32, rois [256,5] f32, out [256,10,7,7] f32.
// CRITICAL numerics (do not touch — r1-r22 forensics):
//  - bin = roi * fl32(1/7)  (reciprocal multiply, NOT division)
//  - boundary = fl32(fl32(p*bin) + start): two roundings, fma blocked.
// r24 lesson: UNconditional clamped loads (49/lane) -> 8x L2 transactions
// (lanes hit different planes; zero coalescing) -> 30 µs. r25: full unroll
// with PREDICATED loads (exec-masked: only in-window lanes issue
// transactions) -> r23's transaction count, but loads issue in independent
// bursts instead of load->wait->add serialization. Masked +0.0f adds in
// ascending (h,w) order keep the sum bit-identical to r23.

#pragma clang fp contract(off)

#define PS 7
#define DD 10
#define CC 490
#define HH 38
#define WW 38

__device__ __forceinline__ float mul_add_strict_f32(float a, float b, float c) {
#pragma clang fp contract(off)
    float p = a * b;
    asm volatile("" : "+v"(p));   // block fma contraction
    return p + c;
}

__global__ __launch_bounds__(256) void psroi_pool_kernel(
    const float* __restrict__ feat,
    const float* __restrict__ rois,
    float* __restrict__ out,
    int total)
{
#pragma clang fp contract(off)
    int idx = blockIdx.x * blockDim.x + threadIdx.x;
    if (idx >= total) return;

    int pw = idx % PS;
    int ph = (idx / PS) % PS;
    int d  = (idx / (PS * PS)) % DD;
    int r  = idx / (PS * PS * DD);

    const float* roi = rois + (size_t)r * 5;
    int b = (int)roi[0];

    float xs = rintf(roi[1]) * 0.0625f;
    float ys = rintf(roi[2]) * 0.0625f;
    float xe = rintf(roi[3] + 1.0f) * 0.0625f;
    float ye = rintf(roi[4] + 1.0f) * 0.0625f;

    float roi_w = fmaxf(xe - xs, 0.1f);
    float roi_h = fmaxf(ye - ys, 0.1f);

    // RECIPROCAL MULTIPLY (verified): bin = roi * fl32(1/7)
    const float RECIP7 = 1.0f / 7.0f;
    float bin_w = roi_w * RECIP7;
    float bin_h = roi_h * RECIP7;

    float hs_f = floorf(mul_add_strict_f32((float)ph,       bin_h, ys));
    float he_f = ceilf (mul_add_strict_f32((float)(ph + 1), bin_h, ys));
    float ws_f = floorf(mul_add_strict_f32((float)pw,       bin_w, xs));
    float we_f = ceilf (mul_add_strict_f32((float)(pw + 1), bin_w, xs));

    int hstart = (int)fminf(fmaxf(hs_f, 0.0f), (float)HH);
    int hend   = (int)fminf(fmaxf(he_f, 0.0f), (float)HH);
    int wstart = (int)fminf(fmaxf(ws_f, 0.0f), (float)WW);
    int wend   = (int)fminf(fmaxf(we_f, 0.0f), (float)WW);

    int c = (d * PS + ph) * PS + pw;
    const float* fp = feat + ((size_t)b * CC + c) * (HH * WW);

    // Fully unrolled, PREDICATED window sum. Loads execute only for
    // in-window (h,w) (exec-masked -> no extra L2 transactions); per-row
    // loads are issued as an independent burst into v[0..6], then added in
    // ascending order (masked +0.0f) — bit-identical to the r23 sum.
    float sum = 0.0f;
#pragma unroll
    for (int hh = 0; hh < 7; ++hh) {
        int h = hstart + hh;
        bool vh = (h < hend);
        const float* row = fp + h * WW;
        float v[7];
#pragma unroll
        for (int ww = 0; ww < 7; ++ww) {
            int w = wstart + ww;
            v[ww] = (vh && w < wend) ? row[w] : 0.0f;
        }
#pragma unroll
        for (int ww = 0; ww < 7; ++ww) {
            sum += v[ww];
        }
    }

    int cnt = (hend - hstart) * (wend - wstart);
    out[idx] = (cnt > 0) ? (sum / (float)cnt) : 0.0f;
}

extern "C" void kernel_launch(void* const* d_in, const int* in_sizes, int n_in,
                              void* d_out, int out_size, void* d_ws, size_t ws_size,
                              hipStream_t stream) {
    const float* feat = (const float*)d_in[0];
    const float* rois = (const float*)d_in[1];
    float* out = (float*)d_out;

    int total = out_size;  // 125440
    int block = 256;
    int grid = (total + block - 1) / block;
    psroi_pool_kernel<<<grid, block, 0, stream>>>(feat, rois, out, total);
}